// Round 13
// baseline (47.844 us; speedup 1.0000x reference)
//
#include <hip/hip_runtime.h>
#include <hip/hip_bf16.h>
#include <math.h>

// MultiVariateAttention: out[b,u] = exp(mvn_logpdf(x[b]; mu[u], diag(s[u])))
// B = U = 4096, D = 16, fp32 in/out.
//
// R13 = DIAGNOSTIC round (pre-committed in R12): R11's kernel (22.5us best)
// with the main loop executed REP=3 times, each rep recomputing and
// re-storing IDENTICAL values (opaque register barrier defeats CSE; stores
// are idempotent -> output bit-identical, deterministic, graph-safe).
// Purpose: kernel dur ~60us > the 41-48us harness fills -> our kernel's own
// rocprof counters (VALUBusy / Occupancy / WRITE_SIZE / bank conflicts)
// finally appear in top-5. dur/3 also calibrates true kernel time.

#define TPB 256
#define DD  16
#define UB  32     // u's per block
#define BB  512    // b's per block; grid (128, 8) = 1024 blocks = 4/CU

typedef float v2f __attribute__((ext_vector_type(2)));

static constexpr float L2E   = 1.4426950408889634f;   // log2(e)
static constexpr float HL2PI = 0.91893853320467274f;  // 0.5*ln(2*pi)

template <int REP>
__global__ __launch_bounds__(TPB, 4) void mva_tile(
    const float* __restrict__ x,      // [B,1,D]
    const float* __restrict__ units,  // [U,D]
    const float* __restrict__ attn,   // [U,D,D]
    float* __restrict__ out,          // [B,U]
    int U)
{
    const int tid    = threadIdx.x;
    const int u_base = blockIdx.x * UB;
    const int b_base = blockIdx.y * BB;

    __shared__ float xs[BB][DD];          // 32 KB
    __shared__ float a1L[DD][UB + 2];
    __shared__ float a2L[DD][UB + 2];
    __shared__ float biasL[UB];

    // ---- stage x tile (coalesced float4, 8 per thread) ----
    const float* xb = x + (size_t)b_base * DD;
#pragma unroll
    for (int r = 0; r < (BB * DD) / (TPB * 4); ++r) {  // 8 iters
        const int q = (r * TPB + tid) * 4;
        *reinterpret_cast<float4*>(&xs[0][0] + q) =
            *reinterpret_cast<const float4*>(xb + q);
    }

    // ---- param gather: 512 (u,d)-pairs over 256 threads (2 d's each) ----
    {
        const int ul = tid >> 3;          // 0..31  local u
        const int d0 = (tid & 7) * 2;     // 0,2,..,14
        const int u  = u_base + ul;
        float2 m = *reinterpret_cast<const float2*>(units + (size_t)u * DD + d0);
        const float* ar = attn + (size_t)u * DD * DD;
        float s0 = fmaxf(ar[d0 * (DD + 1)], 1e-6f);
        float s1 = fmaxf(ar[(d0 + 1) * (DD + 1)], 1e-6f);
        float w0 = 1.f / (s0 * s0);
        float w1 = 1.f / (s1 * s1);
        a1L[d0][ul]     = L2E * m.x * w0;
        a2L[d0][ul]     = -0.5f * L2E * w0;
        a1L[d0 + 1][ul] = L2E * m.y * w1;
        a2L[d0 + 1][ul] = -0.5f * L2E * w1;
        float bn = -0.5f * (m.x * m.x * w0 + m.y * m.y * w1)
                 - (logf(s0) + logf(s1));
        bn += __shfl_xor(bn, 1, 8);
        bn += __shfl_xor(bn, 2, 8);
        bn += __shfl_xor(bn, 4, 8);
        if ((tid & 7) == 0) biasL[ul] = L2E * (bn - DD * HL2PI);
    }
    __syncthreads();

    // ---- pull this thread's u-pair params into registers (packed) ----
    const int up = tid & 15;              // u-pair index: u = u_base + up*2
    const int br = tid >> 4;              // b-row offset 0..15
    v2f a1p[DD], a2p[DD];
#pragma unroll
    for (int d = 0; d < DD; ++d) {
        a1p[d] = *reinterpret_cast<const v2f*>(&a1L[d][up * 2]);
        a2p[d] = *reinterpret_cast<const v2f*>(&a2L[d][up * 2]);
    }
    const v2f biasp = *reinterpret_cast<const v2f*>(&biasL[up * 2]);

    float* orow = out + (size_t)b_base * U + u_base + up * 2;

#pragma unroll 1
    for (int rep = 0; rep < REP; ++rep) {
        // Opaque pass-through: forces the full FMA chain + stores to
        // re-execute each rep with bit-identical results (no CSE).
        v2f biasr = biasp;
        asm volatile("" : "+v"(biasr));

#pragma unroll 2
        for (int it = 0; it < BB / 16; ++it) {
            const int b = it * 16 + br;
            v2f acc = biasr;
#pragma unroll
            for (int j = 0; j < 4; ++j) {
                float4 xv = *reinterpret_cast<const float4*>(&xs[b][4 * j]);
                const int d = 4 * j;
                v2f xx, t;
                xx = (v2f){xv.x, xv.x};
                t   = __builtin_elementwise_fma(xx, a2p[d + 0], a1p[d + 0]);
                acc = __builtin_elementwise_fma(xx, t, acc);
                xx = (v2f){xv.y, xv.y};
                t   = __builtin_elementwise_fma(xx, a2p[d + 1], a1p[d + 1]);
                acc = __builtin_elementwise_fma(xx, t, acc);
                xx = (v2f){xv.z, xv.z};
                t   = __builtin_elementwise_fma(xx, a2p[d + 2], a1p[d + 2]);
                acc = __builtin_elementwise_fma(xx, t, acc);
                xx = (v2f){xv.w, xv.w};
                t   = __builtin_elementwise_fma(xx, a2p[d + 3], a1p[d + 3]);
                acc = __builtin_elementwise_fma(xx, t, acc);
            }
            float2 o;
            o.x = __builtin_amdgcn_exp2f(acc[0]);
            o.y = __builtin_amdgcn_exp2f(acc[1]);
            *reinterpret_cast<float2*>(orow + (size_t)b * U) = o;
        }
    }
}

extern "C" void kernel_launch(void* const* d_in, const int* in_sizes, int n_in,
                              void* d_out, int out_size, void* d_ws, size_t ws_size,
                              hipStream_t stream) {
    const float* x     = (const float*)d_in[0];  // [B,1,D]
    const float* units = (const float*)d_in[1];  // [U,D]
    const float* attn  = (const float*)d_in[2];  // [U,D,D]
    float* out = (float*)d_out;

    const int B = in_sizes[0] / DD;  // 4096
    const int U = in_sizes[1] / DD;  // 4096

    dim3 grid(U / UB, B / BB);       // (128, 8) = 1024 blocks
    mva_tile<3><<<grid, TPB, 0, stream>>>(x, units, attn, out, U);
}

// Round 14
// 25.339 us; speedup vs baseline: 1.8882x; 1.8882x over previous
//
#include <hip/hip_runtime.h>
#include <hip/hip_bf16.h>
#include <math.h>

// MultiVariateAttention: out[b,u] = exp(mvn_logpdf(x[b]; mu[u], diag(s[u])))
// B = U = 4096, D = 16, fp32 in/out.
//
// R14 = R11 body + store-path retile (R13 diagnostic: VALU at floor (59%
// busy = 9us/rep), stores at 4.2 of 6.3 TB/s, loop 15.3 vs 10.2 floor):
//  - tile 128u x 128b: one wave-store = 512 B CONTIGUOUS (64 lanes x 8B,
//    single b-row), was 4x128B fragments at 16KB stride.
//  - XCD band remap: xcd = bid&7 owns u-chunks [xcd*4, xcd*4+4) -> each
//    L2 receives adjacent-u stores that merge into 2KB runs per row.
//  - params through LDS (R8 lesson); gather issued scatter-first.

#define TPB 256
#define DD  16
#define UB  128    // u's per block
#define BB  128    // b's per block; 32x32 = 1024 blocks = 4/CU

typedef float v2f __attribute__((ext_vector_type(2)));

static constexpr float L2E   = 1.4426950408889634f;   // log2(e)
static constexpr float HL2PI = 0.91893853320467274f;  // 0.5*ln(2*pi)

__global__ __launch_bounds__(TPB, 4) void mva_tile(
    const float* __restrict__ x,      // [B,1,D]
    const float* __restrict__ units,  // [U,D]
    const float* __restrict__ attn,   // [U,D,D]
    float* __restrict__ out,          // [B,U]
    int U)
{
    const int tid = threadIdx.x;
    // XCD band remap: hw round-robins blockIdx over 8 XCDs.
    const int k   = blockIdx.x;
    const int xcd = k & 7;
    const int j   = k >> 3;            // 0..127
    const int uc  = xcd * 4 + (j & 3); // 0..31 : XCD owns 4 adjacent u-chunks
    const int bc  = j >> 2;            // 0..31
    const int u_base = uc * UB;
    const int b_base = bc * BB;

    __shared__ float xs[BB][DD];        // 8 KB
    __shared__ float a1L[DD][UB + 2];   // 8.1 KB (pad keeps v2f alignment)
    __shared__ float a2L[DD][UB + 2];
    __shared__ float bp[2][UB];         // bias partials (two d-halves)

    // ---- param gather FIRST (scattered = longest latency) ----
    {
        const int ul   = tid & 127;     // local u
        const int half = tid >> 7;      // 0,1
        const int d0   = half * 8;
        const int u    = u_base + ul;
        const float* ar = attn + (size_t)u * DD * DD;
        float4 m0 = *reinterpret_cast<const float4*>(units + (size_t)u * DD + d0);
        float4 m1 = *reinterpret_cast<const float4*>(units + (size_t)u * DD + d0 + 4);
        const float mu[8] = {m0.x, m0.y, m0.z, m0.w, m1.x, m1.y, m1.z, m1.w};
        float bn = 0.f;
#pragma unroll
        for (int dd = 0; dd < 8; ++dd) {
            const int d = d0 + dd;
            float s = fmaxf(ar[d * (DD + 1)], 1e-6f);
            float w = 1.f / (s * s);
            a1L[d][ul] = L2E * mu[dd] * w;
            a2L[d][ul] = -0.5f * L2E * w;
            bn += -0.5f * mu[dd] * mu[dd] * w - logf(s);
        }
        bp[half][ul] = bn;
    }

    // ---- x tile: 2 coalesced float4 per thread (8 KB) ----
    const float* xb = x + (size_t)b_base * DD;
#pragma unroll
    for (int r = 0; r < (BB * DD) / (TPB * 4); ++r) {  // 2 iters
        const int q = (r * TPB + tid) * 4;
        *reinterpret_cast<float4*>(&xs[0][0] + q) =
            *reinterpret_cast<const float4*>(xb + q);
    }
    __syncthreads();

    // ---- per-thread u-pair params from LDS (broadcast-friendly) ----
    const int up = tid & 63;            // u-pair: u = u_base + up*2
    const int br = tid >> 6;            // 0..3 concurrent b-rows
    v2f a1p[DD], a2p[DD];
#pragma unroll
    for (int d = 0; d < DD; ++d) {
        a1p[d] = *reinterpret_cast<const v2f*>(&a1L[d][up * 2]);
        a2p[d] = *reinterpret_cast<const v2f*>(&a2L[d][up * 2]);
    }
    v2f biasp;
    {
        v2f b0 = *reinterpret_cast<const v2f*>(&bp[0][up * 2]);
        v2f b1 = *reinterpret_cast<const v2f*>(&bp[1][up * 2]);
        biasp[0] = L2E * (b0[0] + b1[0] - DD * HL2PI);
        biasp[1] = L2E * (b0[1] + b1[1] - DD * HL2PI);
    }

    // ---- main loop: 32 iters x 4 rows; wave-store = 512B contiguous ----
    float* orow = out + (size_t)b_base * U + u_base + up * 2;
#pragma unroll 2
    for (int it = 0; it < BB / 4; ++it) {
        const int b = it * 4 + br;
        v2f acc = biasp;
#pragma unroll
        for (int jj = 0; jj < 4; ++jj) {
            // all 64 lanes of a wave share b -> full-wave LDS broadcast
            float4 xv = *reinterpret_cast<const float4*>(&xs[b][4 * jj]);
            const int d = 4 * jj;
            v2f xx, t;
            xx = (v2f){xv.x, xv.x};
            t   = __builtin_elementwise_fma(xx, a2p[d + 0], a1p[d + 0]);
            acc = __builtin_elementwise_fma(xx, t, acc);
            xx = (v2f){xv.y, xv.y};
            t   = __builtin_elementwise_fma(xx, a2p[d + 1], a1p[d + 1]);
            acc = __builtin_elementwise_fma(xx, t, acc);
            xx = (v2f){xv.z, xv.z};
            t   = __builtin_elementwise_fma(xx, a2p[d + 2], a1p[d + 2]);
            acc = __builtin_elementwise_fma(xx, t, acc);
            xx = (v2f){xv.w, xv.w};
            t   = __builtin_elementwise_fma(xx, a2p[d + 3], a1p[d + 3]);
            acc = __builtin_elementwise_fma(xx, t, acc);
        }
        float2 o;
        o.x = __builtin_amdgcn_exp2f(acc[0]);
        o.y = __builtin_amdgcn_exp2f(acc[1]);
        *reinterpret_cast<float2*>(orow + (size_t)b * U) = o;
    }
}

extern "C" void kernel_launch(void* const* d_in, const int* in_sizes, int n_in,
                              void* d_out, int out_size, void* d_ws, size_t ws_size,
                              hipStream_t stream) {
    const float* x     = (const float*)d_in[0];  // [B,1,D]
    const float* units = (const float*)d_in[1];  // [U,D]
    const float* attn  = (const float*)d_in[2];  // [U,D,D]
    float* out = (float*)d_out;

    const int B = in_sizes[0] / DD;  // 4096
    const int U = in_sizes[1] / DD;  // 4096

    const int nblk = (U / UB) * (B / BB);  // 32*32 = 1024
    mva_tile<<<nblk, TPB, 0, stream>>>(x, units, attn, out, U);
}

// Round 15
// 24.110 us; speedup vs baseline: 1.9844x; 1.0510x over previous
//
#include <hip/hip_runtime.h>
#include <hip/hip_bf16.h>
#include <math.h>

// MultiVariateAttention: out[b,u] = exp(mvn_logpdf(x[b]; mu[u], diag(s[u])))
// B = U = 4096, D = 16, fp32 in/out.
//
// R15: one block per CU + max-efficiency LDS reads.
//  - R13 accounting: loop 15.3us = store floor 10.2 + UNMODELED LDS pipe
//    (~10us: broadcast b128 = only 64B useful). Fix: 8-lane row groups +
//    xs row stride 20 floats -> one ds_read_b128 serves 8 rows x 16B =
//    128B, conflict-free (banks {0,20,8,28,16,4,24,12}+j*4 cover all 32).
//    u-quad per lane (4 u) halves read count; 4 pk_fma per x-broadcast.
//  - TPB=512, UB=32, BB=2048 in 4 double-buffered phases: grid = 256
//    blocks = exactly 1/CU, ONE generation; params gathered once per
//    block (8MB total L2 traffic); prologue exposed once.
//  - stage(ph+1) issues BEFORE compute(ph): its vmcnt wait sees zero
//    outstanding stores (in-order counter), stores stream un-awaited.

#define TPB  512
#define DD   16
#define UB   32      // u per block = 8 quads of 4
#define BCH  512     // b rows per phase
#define NPH  4       // phases -> 2048 b rows per block
#define XST  (DD + 4)  // xs row stride 20 floats: conflict-free + 16B-aligned

typedef float v2f __attribute__((ext_vector_type(2)));

static constexpr float L2E   = 1.4426950408889634f;   // log2(e)
static constexpr float HL2PI = 0.91893853320467274f;  // 0.5*ln(2*pi)

__global__ __launch_bounds__(TPB, 2) void mva_big(
    const float* __restrict__ x,      // [B,1,D]
    const float* __restrict__ units,  // [U,D]
    const float* __restrict__ attn,   // [U,D,D]
    float* __restrict__ out,          // [B,U]
    int U)
{
    const int tid    = threadIdx.x;
    const int u_base = blockIdx.x * UB;
    const int b_base = blockIdx.y * (BCH * NPH);

    __shared__ __align__(16) float xs[2][BCH][XST];   // 80 KB double buffer
    __shared__ __align__(16) float a1L[DD][UB + 4];   // stride 36: aligned
    __shared__ __align__(16) float a2L[DD][UB + 4];
    __shared__ __align__(16) float biasL[UB];

    // ---- param gather: one (u,d) per thread (512 = 32u x 16d) ----
    {
        const int ul = tid >> 4, d = tid & 15;
        const int u  = u_base + ul;
        float s  = fmaxf(attn[(size_t)u * DD * DD + d * (DD + 1)], 1e-6f);
        float w  = 1.f / (s * s);
        float mu = units[u * DD + d];
        a1L[d][ul] = L2E * mu * w;
        a2L[d][ul] = -0.5f * L2E * w;
        float bn = -0.5f * mu * mu * w - logf(s);
        bn += __shfl_xor(bn, 1, 16);
        bn += __shfl_xor(bn, 2, 16);
        bn += __shfl_xor(bn, 4, 16);
        bn += __shfl_xor(bn, 8, 16);
        if (d == 0) biasL[ul] = L2E * (bn - DD * HL2PI);
    }

    // ---- stage helper: 512 rows x 16 floats -> padded xs buffer ----
    auto stage = [&](int ph) {
        const float* xb = x + (size_t)(b_base + ph * BCH) * DD;
        float* dst = &xs[ph & 1][0][0];
#pragma unroll
        for (int r = 0; r < (BCH * DD) / (TPB * 4); ++r) {  // 4 iters
            const int q   = (r * TPB + tid) * 4;
            const int row = q >> 4, col = q & 15;
            *reinterpret_cast<float4*>(dst + row * XST + col) =
                *reinterpret_cast<const float4*>(xb + q);
        }
    };

    stage(0);
    __syncthreads();

    // ---- per-lane u-quad params from LDS (conflict-free float4 reads) ----
    const int uq = tid & 7;            // u = u_base + uq*4 .. +3
    const int br = tid >> 3;           // 64 concurrent b rows
    v2f a1A[DD], a1B[DD], a2A[DD], a2B[DD];
#pragma unroll
    for (int d = 0; d < DD; ++d) {
        float4 q1 = *reinterpret_cast<const float4*>(&a1L[d][uq * 4]);
        a1A[d] = (v2f){q1.x, q1.y};  a1B[d] = (v2f){q1.z, q1.w};
        float4 q2 = *reinterpret_cast<const float4*>(&a2L[d][uq * 4]);
        a2A[d] = (v2f){q2.x, q2.y};  a2B[d] = (v2f){q2.z, q2.w};
    }
    float4 bq = *reinterpret_cast<const float4*>(&biasL[uq * 4]);
    const v2f biasA = (v2f){bq.x, bq.y}, biasB = (v2f){bq.z, bq.w};

    // ---- 4 phases: prefetch next buffer, compute current ----
#pragma unroll 1
    for (int ph = 0; ph < NPH; ++ph) {
        if (ph + 1 < NPH) stage(ph + 1);   // other buffer; no race
        const float* xp = &xs[ph & 1][0][0];
        float* ob = out + (size_t)(b_base + ph * BCH) * U + u_base + uq * 4;

#pragma unroll 2
        for (int it = 0; it < BCH / 64; ++it) {   // 8 iters
            const int b = it * 64 + br;
            const float* xr = xp + b * XST;
            v2f accA = biasA, accB = biasB;
#pragma unroll
            for (int j = 0; j < 4; ++j) {
                // one ds_read_b128: 8 rows x 16B across all 32 banks
                float4 xv = *reinterpret_cast<const float4*>(xr + 4 * j);
                const int d = 4 * j;
                v2f xx, t;
                xx = (v2f){xv.x, xv.x};
                t = __builtin_elementwise_fma(xx, a2A[d + 0], a1A[d + 0]);
                accA = __builtin_elementwise_fma(xx, t, accA);
                t = __builtin_elementwise_fma(xx, a2B[d + 0], a1B[d + 0]);
                accB = __builtin_elementwise_fma(xx, t, accB);
                xx = (v2f){xv.y, xv.y};
                t = __builtin_elementwise_fma(xx, a2A[d + 1], a1A[d + 1]);
                accA = __builtin_elementwise_fma(xx, t, accA);
                t = __builtin_elementwise_fma(xx, a2B[d + 1], a1B[d + 1]);
                accB = __builtin_elementwise_fma(xx, t, accB);
                xx = (v2f){xv.z, xv.z};
                t = __builtin_elementwise_fma(xx, a2A[d + 2], a1A[d + 2]);
                accA = __builtin_elementwise_fma(xx, t, accA);
                t = __builtin_elementwise_fma(xx, a2B[d + 2], a1B[d + 2]);
                accB = __builtin_elementwise_fma(xx, t, accB);
                xx = (v2f){xv.w, xv.w};
                t = __builtin_elementwise_fma(xx, a2A[d + 3], a1A[d + 3]);
                accA = __builtin_elementwise_fma(xx, t, accA);
                t = __builtin_elementwise_fma(xx, a2B[d + 3], a1B[d + 3]);
                accB = __builtin_elementwise_fma(xx, t, accB);
            }
            float4 o;
            o.x = __builtin_amdgcn_exp2f(accA[0]);
            o.y = __builtin_amdgcn_exp2f(accA[1]);
            o.z = __builtin_amdgcn_exp2f(accB[0]);
            o.w = __builtin_amdgcn_exp2f(accB[1]);
            // 8 lanes/group x 16B = 512B contiguous per row
            *reinterpret_cast<float4*>(ob + (size_t)b * U) = o;
        }
        __syncthreads();   // release buffer for stage(ph+2)
    }
}

extern "C" void kernel_launch(void* const* d_in, const int* in_sizes, int n_in,
                              void* d_out, int out_size, void* d_ws, size_t ws_size,
                              hipStream_t stream) {
    const float* x     = (const float*)d_in[0];  // [B,1,D]
    const float* units = (const float*)d_in[1];  // [U,D]
    const float* attn  = (const float*)d_in[2];  // [U,D,D]
    float* out = (float*)d_out;

    const int B = in_sizes[0] / DD;  // 4096
    const int U = in_sizes[1] / DD;  // 4096

    dim3 grid(U / UB, B / (BCH * NPH));  // (128, 2) = 256 blocks = 1/CU
    mva_big<<<grid, TPB, 0, stream>>>(x, units, attn, out, U);
}